// Round 1
// baseline (1236.251 us; speedup 1.0000x reference)
//
#include <hip/hip_runtime.h>

// EdgeConvEncoder: 3 fused EdgeConv layers (bf16 MFMA q/k/v projection,
// wave-local softmax, atomic scatter-mean aggregation).
// ws layout: packed bf16 weight fragments (384KB) | s0 (N*128 f32, becomes x0)
//            | s1 (N*64 f32) | cnt0,cnt1,cnt2 (N f32 each).  ~39.4 MB total.

typedef short bf16x8 __attribute__((ext_vector_type(8)));
typedef float f32x4 __attribute__((ext_vector_type(4)));

__device__ __forceinline__ unsigned short f2bf(float f) {
  unsigned int u = __float_as_uint(f);
  u += 0x7FFFu + ((u >> 16) & 1u);  // round-to-nearest-even
  return (unsigned short)(u >> 16);
}

template <int HS>
__device__ __forceinline__ float head_reduce_max(float v) {
  v = fmaxf(v, __shfl_xor(v, 1));
  v = fmaxf(v, __shfl_xor(v, 2));
  v = fmaxf(v, __shfl_xor(v, 4));
  if (HS == 16) v = fmaxf(v, __shfl_xor(v, 8));
  return v;
}
template <int HS>
__device__ __forceinline__ float head_reduce_sum(float v) {
  v += __shfl_xor(v, 1);
  v += __shfl_xor(v, 2);
  v += __shfl_xor(v, 4);
  if (HS == 16) v += __shfl_xor(v, 8);
  return v;
}

// Pack a K x O fp32 weight matrix (x3: q,k,v) into MFMA B-fragment order:
// frag (mat, nc, kc): lane l, j -> W[kc*32 + (l>>4)*8 + j][nc*16 + (l&15)]
__global__ void pack_weights(const float* __restrict__ wq, const float* __restrict__ wk,
                             const float* __restrict__ wv, unsigned short* __restrict__ dst,
                             int K, int O) {
  int id = blockIdx.x * blockDim.x + threadIdx.x;
  int kchunks = K >> 5, nchunks = O >> 4;
  int total = 3 * nchunks * kchunks * 64;
  if (id >= total) return;
  int lane = id & 63;
  int frag = id >> 6;
  int kc = frag % kchunks;
  int nc = (frag / kchunks) % nchunks;
  int mat = frag / (kchunks * nchunks);
  const float* w = (mat == 0) ? wq : (mat == 1) ? wk : wv;
  int n = nc * 16 + (lane & 15);
  int k0 = kc * 32 + (lane >> 4) * 8;
  unsigned short tmp[8];
#pragma unroll
  for (int j = 0; j < 8; ++j) tmp[j] = f2bf(w[(size_t)(k0 + j) * O + n]);
  uint4 o;
  o.x = (unsigned)tmp[0] | ((unsigned)tmp[1] << 16);
  o.y = (unsigned)tmp[2] | ((unsigned)tmp[3] << 16);
  o.z = (unsigned)tmp[4] | ((unsigned)tmp[5] << 16);
  o.w = (unsigned)tmp[6] | ((unsigned)tmp[7] << 16);
  reinterpret_cast<uint4*>(dst)[id] = o;
}

// One EdgeConv layer, fused: gather -> feat(bf16, LDS) -> q/k/v MFMA ->
// bias + softmax(q*k*scale) -> ctx = probs*v*ew -> atomic scatter into s,
// edge count into cnt.
// Block: 256 threads = 4 waves, 64 edges. Wave w owns head-chunk subset
// {NCPM*w .. NCPM*w+NCPM} of each of q,k,v so softmax is wave-local.
template <int IN, int O, int HS>
__global__ __launch_bounds__(256, 2) void edge_conv_kernel(
    const float* __restrict__ x, const int* __restrict__ eidx, const int E,
    const unsigned short* __restrict__ wpack, const float* __restrict__ bq,
    const float* __restrict__ bk, const float* __restrict__ bv,
    float* __restrict__ s, float* __restrict__ cnt) {
  constexpr int K = 2 * IN;
  constexpr int KC = K / 32;    // k-chunks of 32
  constexpr int NCH = O / 16;   // 16-col chunks per matrix
  constexpr int NCPM = O / 64;  // chunks per matrix per wave (2 or 1)
  constexpr int STR = K + 8;    // LDS row stride in bf16 (+8: 2-way bank alias = free)
  constexpr float scale = (HS == 16) ? 0.25f : 0.35355339059327373f;

  __shared__ unsigned short feat[64 * STR];
  __shared__ int dstL[64];
  __shared__ float ewL[64];

  const int t = threadIdx.x;
  const int eL = t >> 2;  // edge-in-block 0..63
  const int q4 = t & 3;   // quarter of the feature row
  const int e0 = blockIdx.x * 64;
  const int eG = e0 + eL;
  const bool valid = (eG < E);

  int srcN = 0, dstN = 0;
  if (valid) {
    srcN = eidx[eG];
    dstN = eidx[E + eG];
  }
  if (q4 == 0) {
    dstL[eL] = dstN;
    float dd = fabsf((float)(dstN - srcN));
    // sign(log d - log 8): d>8 -> +1, d==8 -> 0, d<8 (incl. 0) -> -1
    ewL[eL] = (dd > 8.0f) ? 1.0f : ((dd == 8.0f) ? 0.0f : -1.0f);
    if (valid) atomicAdd(&cnt[dstN], 1.0f);
  }

  {  // stage feat = [xi, xj - xi] as bf16 into LDS
    constexpr int QF = IN / 4;  // floats per quarter
    const float* xi = x + (size_t)dstN * IN + q4 * QF;
    const float* xj = x + (size_t)srcN * IN + q4 * QF;
    unsigned short* frow = &feat[eL * STR + q4 * QF];
#pragma unroll
    for (int c = 0; c < QF / 4; ++c) {
      float4 a, b;
      if (valid) {
        a = *reinterpret_cast<const float4*>(xi + c * 4);
        b = *reinterpret_cast<const float4*>(xj + c * 4);
      } else {
        a = make_float4(0.f, 0.f, 0.f, 0.f);
        b = make_float4(0.f, 0.f, 0.f, 0.f);
      }
      ushort4 ua = make_ushort4(f2bf(a.x), f2bf(a.y), f2bf(a.z), f2bf(a.w));
      ushort4 ud = make_ushort4(f2bf(b.x - a.x), f2bf(b.y - a.y),
                                f2bf(b.z - a.z), f2bf(b.w - a.w));
      *reinterpret_cast<ushort4*>(frow + c * 4) = ua;
      *reinterpret_cast<ushort4*>(frow + IN + c * 4) = ud;
    }
  }
  __syncthreads();

  const int w = t >> 6;
  const int ln = t & 63;
  const int col = ln & 15;
  const int quad = ln >> 4;

  f32x4 acc[3 * NCPM][4];
#pragma unroll
  for (int c = 0; c < 3 * NCPM; ++c)
#pragma unroll
    for (int m = 0; m < 4; ++m) acc[c][m] = (f32x4){0.f, 0.f, 0.f, 0.f};

  for (int kc = 0; kc < KC; ++kc) {
    bf16x8 a[4];
#pragma unroll
    for (int m = 0; m < 4; ++m)
      a[m] = *reinterpret_cast<const bf16x8*>(
          &feat[(m * 16 + col) * STR + kc * 32 + quad * 8]);
#pragma unroll
    for (int c = 0; c < 3 * NCPM; ++c) {
      const int mat = c / NCPM;
      const int ncg = NCPM * w + (c % NCPM);
      const bf16x8 b = *reinterpret_cast<const bf16x8*>(
          wpack + ((size_t)((mat * NCH + ncg) * KC + kc) * 64 + ln) * 8);
#pragma unroll
      for (int m = 0; m < 4; ++m)
        acc[c][m] = __builtin_amdgcn_mfma_f32_16x16x32_bf16(a[m], b, acc[c][m], 0, 0, 0);
    }
  }

  // Epilogue. C-frag mapping: col = ln&15, row = quad*4 + r (edge in m-tile).
#pragma unroll
  for (int hh = 0; hh < NCPM; ++hh) {
    const int colg = (NCPM * w + hh) * 16 + col;
    const float bqv = bq[colg], bkv = bk[colg], bvv = bv[colg];
#pragma unroll
    for (int m = 0; m < 4; ++m) {
      const f32x4 qf = acc[hh][m];
      const f32x4 kf = acc[NCPM + hh][m];
      const f32x4 vf = acc[2 * NCPM + hh][m];
#pragma unroll
      for (int r = 0; r < 4; ++r) {
        const int eRow = m * 16 + quad * 4 + r;
        const int eGr = e0 + eRow;
        float lg = (qf[r] + bqv) * (kf[r] + bkv) * scale;
        float mx = head_reduce_max<HS>(lg);
        float ex = __expf(lg - mx);
        float sm = head_reduce_sum<HS>(ex);
        float ctx = (ex / sm) * (vf[r] + bvv) * ewL[eRow];
        if (eGr < E) atomicAdd(&s[(size_t)dstL[eRow] * O + colg], ctx);
      }
    }
  }
}

// out = relu(s / max(cnt,1)) in place. One float4 per thread.
__global__ void finalize_relu(float* __restrict__ s, const float* __restrict__ cnt,
                              int total4, int Odiv4) {
  int i = blockIdx.x * blockDim.x + threadIdx.x;
  if (i >= total4) return;
  float c = fmaxf(cnt[i / Odiv4], 1.0f);
  float4 v = reinterpret_cast<float4*>(s)[i];
  v.x = fmaxf(v.x / c, 0.f);
  v.y = fmaxf(v.y / c, 0.f);
  v.z = fmaxf(v.z / c, 0.f);
  v.w = fmaxf(v.w / c, 0.f);
  reinterpret_cast<float4*>(s)[i] = v;
}

// out = relu(out / max(cnt,1) + x0) in place.
__global__ void finalize_add_relu(float* __restrict__ out, const float* __restrict__ x0,
                                  const float* __restrict__ cnt, int total4, int Odiv4) {
  int i = blockIdx.x * blockDim.x + threadIdx.x;
  if (i >= total4) return;
  float c = fmaxf(cnt[i / Odiv4], 1.0f);
  float4 v = reinterpret_cast<float4*>(out)[i];
  float4 r = reinterpret_cast<const float4*>(x0)[i];
  v.x = fmaxf(v.x / c + r.x, 0.f);
  v.y = fmaxf(v.y / c + r.y, 0.f);
  v.z = fmaxf(v.z / c + r.z, 0.f);
  v.w = fmaxf(v.w / c + r.w, 0.f);
  reinterpret_cast<float4*>(out)[i] = v;
}

extern "C" void kernel_launch(void* const* d_in, const int* in_sizes, int n_in,
                              void* d_out, int out_size, void* d_ws, size_t ws_size,
                              hipStream_t stream) {
  const float* x = (const float*)d_in[0];
  const int* e0 = (const int*)d_in[1];
  const int* e1 = (const int*)d_in[2];
  const int* e2 = (const int*)d_in[3];
  const float* wq0 = (const float*)d_in[5];
  const float* bq0 = (const float*)d_in[6];
  const float* wk0 = (const float*)d_in[7];
  const float* bk0 = (const float*)d_in[8];
  const float* wv0 = (const float*)d_in[9];
  const float* bv0 = (const float*)d_in[10];
  const float* wq1 = (const float*)d_in[11];
  const float* bq1 = (const float*)d_in[12];
  const float* wk1 = (const float*)d_in[13];
  const float* bk1 = (const float*)d_in[14];
  const float* wv1 = (const float*)d_in[15];
  const float* bv1 = (const float*)d_in[16];
  const float* wq2 = (const float*)d_in[17];
  const float* bq2 = (const float*)d_in[18];
  const float* wk2 = (const float*)d_in[19];
  const float* bk2 = (const float*)d_in[20];
  const float* wv2 = (const float*)d_in[21];
  const float* bv2 = (const float*)d_in[22];

  const int N = in_sizes[0] / 128;  // 50000
  const int E = in_sizes[1] / 2;    // 500000

  // workspace carve-up
  unsigned short* wp0 = (unsigned short*)d_ws;          // 3*8*8*512 = 98304 shorts
  unsigned short* wp1 = wp0 + 3 * 8 * 8 * 512;          // 3*4*8*512 = 49152
  unsigned short* wp2 = wp1 + 3 * 4 * 8 * 512;          // 3*8*4*512 = 49152
  float* s0 = (float*)(wp2 + 3 * 8 * 4 * 512);          // N*128 (becomes x0)
  float* s1 = s0 + (size_t)N * 128;                     // N*64
  float* c0 = s1 + (size_t)N * 64;                      // N
  float* c1 = c0 + N;
  float* c2 = c1 + N;

  // zero accumulators + counts (contiguous) and output
  hipMemsetAsync(s0, 0, ((size_t)N * 192 + 3 * (size_t)N) * sizeof(float), stream);
  hipMemsetAsync(d_out, 0, (size_t)out_size * sizeof(float), stream);

  pack_weights<<<48, 256, 0, stream>>>(wq0, wk0, wv0, wp0, 256, 128);
  pack_weights<<<24, 256, 0, stream>>>(wq1, wk1, wv1, wp1, 256, 64);
  pack_weights<<<24, 256, 0, stream>>>(wq2, wk2, wv2, wp2, 128, 128);

  const int eb = (E + 63) / 64;
  // layer 0: IN=128, O=128, HS=16
  edge_conv_kernel<128, 128, 16><<<eb, 256, 0, stream>>>(x, e0, E, wp0, bq0, bk0, bv0, s0, c0);
  finalize_relu<<<(N * 32 + 255) / 256, 256, 0, stream>>>(s0, c0, N * 32, 32);
  // layer 1: IN=128, O=64, HS=8
  edge_conv_kernel<128, 64, 8><<<eb, 256, 0, stream>>>(s0, e1, E, wp1, bq1, bk1, bv1, s1, c1);
  finalize_relu<<<(N * 16 + 255) / 256, 256, 0, stream>>>(s1, c1, N * 16, 16);
  // layer 2: IN=64, O=128, HS=16 -> accumulate straight into d_out
  edge_conv_kernel<64, 128, 16><<<eb, 256, 0, stream>>>(s1, e2, E, wp2, bq2, bk2, bv2,
                                                        (float*)d_out, c2);
  finalize_add_relu<<<(N * 32 + 255) / 256, 256, 0, stream>>>((float*)d_out, s0, c2, N * 32, 32);
}

// Round 2
// 949.563 us; speedup vs baseline: 1.3019x; 1.3019x over previous
//
#include <hip/hip_runtime.h>

// EdgeConvEncoder: 3 fused EdgeConv layers.
// R2: counting-sort edges by dst per layer, segmented in-block reduction ->
//     ~8x fewer atomics, sorted addresses; cnt from rowptr; softmax max-pass
//     dropped (shift-invariant, logits << 1).

typedef short bf16x8 __attribute__((ext_vector_type(8)));
typedef float f32x4 __attribute__((ext_vector_type(4)));

__device__ __forceinline__ unsigned short f2bf(float f) {
  unsigned int u = __float_as_uint(f);
  u += 0x7FFFu + ((u >> 16) & 1u);  // round-to-nearest-even
  return (unsigned short)(u >> 16);
}

template <int HS>
__device__ __forceinline__ float head_reduce_sum(float v) {
  v += __shfl_xor(v, 1);
  v += __shfl_xor(v, 2);
  v += __shfl_xor(v, 4);
  if (HS == 16) v += __shfl_xor(v, 8);
  return v;
}

// ---------------- weight packing (unchanged) ----------------
__global__ void pack_weights(const float* __restrict__ wq, const float* __restrict__ wk,
                             const float* __restrict__ wv, unsigned short* __restrict__ dst,
                             int K, int O) {
  int id = blockIdx.x * blockDim.x + threadIdx.x;
  int kchunks = K >> 5, nchunks = O >> 4;
  int total = 3 * nchunks * kchunks * 64;
  if (id >= total) return;
  int lane = id & 63;
  int frag = id >> 6;
  int kc = frag % kchunks;
  int nc = (frag / kchunks) % nchunks;
  int mat = frag / (kchunks * nchunks);
  const float* w = (mat == 0) ? wq : (mat == 1) ? wk : wv;
  int n = nc * 16 + (lane & 15);
  int k0 = kc * 32 + (lane >> 4) * 8;
  unsigned short tmp[8];
#pragma unroll
  for (int j = 0; j < 8; ++j) tmp[j] = f2bf(w[(size_t)(k0 + j) * O + n]);
  uint4 o;
  o.x = (unsigned)tmp[0] | ((unsigned)tmp[1] << 16);
  o.y = (unsigned)tmp[2] | ((unsigned)tmp[3] << 16);
  o.z = (unsigned)tmp[4] | ((unsigned)tmp[5] << 16);
  o.w = (unsigned)tmp[6] | ((unsigned)tmp[7] << 16);
  reinterpret_cast<uint4*>(dst)[id] = o;
}

// ---------------- counting sort by dst (per layer, batched via blockIdx.y) ---
__global__ void hist3(const int* __restrict__ e0, const int* __restrict__ e1,
                      const int* __restrict__ e2, int E, int* __restrict__ hist, int NP) {
  int i = blockIdx.x * blockDim.x + threadIdx.x;
  if (i >= E) return;
  atomicAdd(&hist[0 * NP + e0[E + i]], 1);
  atomicAdd(&hist[1 * NP + e1[E + i]], 1);
  atomicAdd(&hist[2 * NP + e2[E + i]], 1);
}

__device__ __forceinline__ int block_scan_excl256(int v, int* buf, int t, int* total) {
  buf[t] = v;
  __syncthreads();
#pragma unroll
  for (int off = 1; off < 256; off <<= 1) {
    int add = (t >= off) ? buf[t - off] : 0;
    __syncthreads();
    buf[t] += add;
    __syncthreads();
  }
  int incl = buf[t];
  *total = buf[255];
  __syncthreads();
  return incl - v;
}

__global__ void scan_pass1(const int* __restrict__ hist, int* __restrict__ excl,
                           int* __restrict__ bsum, int n, int NP) {
  __shared__ int buf[256];
  int y = blockIdx.y, t = threadIdx.x;
  int i = blockIdx.x * 256 + t;
  int v = (i < n) ? hist[y * NP + i] : 0;
  int total;
  int ex = block_scan_excl256(v, buf, t, &total);
  if (i < NP) excl[y * NP + i] = ex;
  if (t == 0) bsum[y * 256 + blockIdx.x] = total;
}

__global__ void scan_pass2(int* __restrict__ bsum, int nblk) {
  __shared__ int buf[256];
  int y = blockIdx.y, t = threadIdx.x;
  int v = (t < nblk) ? bsum[y * 256 + t] : 0;
  int total;
  int ex = block_scan_excl256(v, buf, t, &total);
  bsum[y * 256 + t] = ex;
}

__global__ void scan_pass3(const int* __restrict__ excl, const int* __restrict__ bsum,
                           int* __restrict__ rowptr, int n, int NP, int RP, int E) {
  int y = blockIdx.y;
  int i = blockIdx.x * 256 + threadIdx.x;
  if (i < n) rowptr[y * RP + i] = excl[y * NP + i] + bsum[y * 256 + blockIdx.x];
  if (i == 0) rowptr[y * RP + n] = E;
}

// scatter, using hist as a count-down fill (saves a buffer + memset)
__global__ void scatter3(const int* __restrict__ e0, const int* __restrict__ e1,
                         const int* __restrict__ e2, int E, const int* __restrict__ rowptr,
                         int* __restrict__ hist, int* __restrict__ srcS,
                         int* __restrict__ dstS, int NP, int RP) {
  int y = blockIdx.y;
  const int* e = (y == 0) ? e0 : (y == 1) ? e1 : e2;
  int i = blockIdx.x * 256 + threadIdx.x;
  if (i >= E) return;
  int sN = e[i], d = e[E + i];
  int old = atomicSub(&hist[y * NP + d], 1);
  int pos = rowptr[y * RP + d] + old - 1;
  srcS[(size_t)y * E + pos] = sN;
  dstS[(size_t)y * E + pos] = d;
}

// ---------------- fused EdgeConv layer ----------------
// Block: 256 threads = 4 waves, 64 dst-sorted edges. Wave w owns head-chunk
// subset of q/k/v columns -> softmax is wave-local. Epilogue writes ctx into
// an LDS tile (union with feat), then a segmented column walk emits one
// atomicAdd per (dst-segment x column).
template <int IN, int O, int HS>
__global__ __launch_bounds__(256, 2) void edge_conv_kernel(
    const float* __restrict__ x, const int* __restrict__ srcS,
    const int* __restrict__ dstS, const int E,
    const unsigned short* __restrict__ wpack, const float* __restrict__ bq,
    const float* __restrict__ bk, const float* __restrict__ bv,
    float* __restrict__ s) {
  constexpr int K = 2 * IN;
  constexpr int KC = K / 32;
  constexpr int NCH = O / 16;
  constexpr int NCPM = O / 64;
  constexpr int STR = K + 8;    // bf16 stride (2-way bank alias = free)
  constexpr int CSTR = O + 4;   // f32 ctx stride
  constexpr float scale = (HS == 16) ? 0.25f : 0.35355339059327373f;

  __shared__ union {
    unsigned short feat[64 * STR];
    float ctx[64 * CSTR];
  } sm;
  __shared__ int dstL[64];
  __shared__ float ewL[64];

  const int t = threadIdx.x;
  const int eL = t >> 2;
  const int q4 = t & 3;
  const int e0 = blockIdx.x * 64;
  const int eG = e0 + eL;
  const bool valid = (eG < E);

  int srcN = 0, dstN = 0;
  if (valid) {
    srcN = srcS[eG];
    dstN = dstS[eG];
  }
  if (q4 == 0) {
    dstL[eL] = dstN;
    float dd = fabsf((float)(dstN - srcN));
    ewL[eL] = (dd > 8.0f) ? 1.0f : ((dd == 8.0f) ? 0.0f : -1.0f);
  }

  {  // stage feat = [xi, xj - xi] as bf16 into LDS
    constexpr int QF = IN / 4;
    const float* xi = x + (size_t)dstN * IN + q4 * QF;
    const float* xj = x + (size_t)srcN * IN + q4 * QF;
    unsigned short* frow = &sm.feat[eL * STR + q4 * QF];
#pragma unroll
    for (int c = 0; c < QF / 4; ++c) {
      float4 a, b;
      if (valid) {
        a = *reinterpret_cast<const float4*>(xi + c * 4);
        b = *reinterpret_cast<const float4*>(xj + c * 4);
      } else {
        a = make_float4(0.f, 0.f, 0.f, 0.f);
        b = make_float4(0.f, 0.f, 0.f, 0.f);
      }
      ushort4 ua = make_ushort4(f2bf(a.x), f2bf(a.y), f2bf(a.z), f2bf(a.w));
      ushort4 ud = make_ushort4(f2bf(b.x - a.x), f2bf(b.y - a.y),
                                f2bf(b.z - a.z), f2bf(b.w - a.w));
      *reinterpret_cast<ushort4*>(frow + c * 4) = ua;
      *reinterpret_cast<ushort4*>(frow + IN + c * 4) = ud;
    }
  }
  __syncthreads();

  const int w = t >> 6;
  const int ln = t & 63;
  const int col = ln & 15;
  const int quad = ln >> 4;

  f32x4 acc[3 * NCPM][4];
#pragma unroll
  for (int c = 0; c < 3 * NCPM; ++c)
#pragma unroll
    for (int m = 0; m < 4; ++m) acc[c][m] = (f32x4){0.f, 0.f, 0.f, 0.f};

  for (int kc = 0; kc < KC; ++kc) {
    bf16x8 a[4];
#pragma unroll
    for (int m = 0; m < 4; ++m)
      a[m] = *reinterpret_cast<const bf16x8*>(
          &sm.feat[(m * 16 + col) * STR + kc * 32 + quad * 8]);
#pragma unroll
    for (int c = 0; c < 3 * NCPM; ++c) {
      const int mat = c / NCPM;
      const int ncg = NCPM * w + (c % NCPM);
      const bf16x8 b = *reinterpret_cast<const bf16x8*>(
          wpack + ((size_t)((mat * NCH + ncg) * KC + kc) * 64 + ln) * 8);
#pragma unroll
      for (int m = 0; m < 4; ++m)
        acc[c][m] = __builtin_amdgcn_mfma_f32_16x16x32_bf16(a[m], b, acc[c][m], 0, 0, 0);
    }
  }

  __syncthreads();  // feat is dead; about to overwrite union with ctx

  // Epilogue: bias + softmax(q*k*scale) + v*ew -> LDS ctx tile.
  // C-frag mapping: col = ln&15, row = quad*4 + r.
#pragma unroll
  for (int hh = 0; hh < NCPM; ++hh) {
    const int colg = (NCPM * w + hh) * 16 + col;
    const float bqv = bq[colg], bkv = bk[colg], bvv = bv[colg];
#pragma unroll
    for (int m = 0; m < 4; ++m) {
      const f32x4 qf = acc[hh][m];
      const f32x4 kf = acc[NCPM + hh][m];
      const f32x4 vf = acc[2 * NCPM + hh][m];
#pragma unroll
      for (int r = 0; r < 4; ++r) {
        const int eRow = m * 16 + quad * 4 + r;
        float lg = (qf[r] + bqv) * (kf[r] + bkv) * scale;
        float ex = __expf(lg);
        float sum = head_reduce_sum<HS>(ex);
        float val = (ex / sum) * (vf[r] + bvv) * ewL[eRow];
        sm.ctx[eRow * CSTR + colg] = (e0 + eRow < E) ? val : 0.f;
      }
    }
  }
  __syncthreads();

  // Segmented reduction over dst-sorted edges: one atomic per segment x col.
  constexpr int EPT = 64 * O / 256;  // edges walked per thread
  const int colA = t % O;
  const int seg0 = (t / O) * EPT;
  float run = 0.f;
  for (int e = seg0; e < seg0 + EPT; ++e) {
    run += sm.ctx[e * CSTR + colA];
    bool bound = (e == seg0 + EPT - 1) || (dstL[e + 1] != dstL[e]);
    if (bound) {
      atomicAdd(&s[(size_t)dstL[e] * O + colA], run);
      run = 0.f;
    }
  }
}

// out = relu(s / max(cnt,1)); cnt = rowptr[n+1]-rowptr[n]
__global__ void finalize_relu(float* __restrict__ s, const int* __restrict__ rowptr,
                              int total4, int Odiv4) {
  int i = blockIdx.x * blockDim.x + threadIdx.x;
  if (i >= total4) return;
  int node = i / Odiv4;
  float c = fmaxf((float)(rowptr[node + 1] - rowptr[node]), 1.0f);
  float4 v = reinterpret_cast<float4*>(s)[i];
  v.x = fmaxf(v.x / c, 0.f);
  v.y = fmaxf(v.y / c, 0.f);
  v.z = fmaxf(v.z / c, 0.f);
  v.w = fmaxf(v.w / c, 0.f);
  reinterpret_cast<float4*>(s)[i] = v;
}

__global__ void finalize_add_relu(float* __restrict__ out, const float* __restrict__ x0,
                                  const int* __restrict__ rowptr, int total4, int Odiv4) {
  int i = blockIdx.x * blockDim.x + threadIdx.x;
  if (i >= total4) return;
  int node = i / Odiv4;
  float c = fmaxf((float)(rowptr[node + 1] - rowptr[node]), 1.0f);
  float4 v = reinterpret_cast<float4*>(out)[i];
  float4 r = reinterpret_cast<const float4*>(x0)[i];
  v.x = fmaxf(v.x / c + r.x, 0.f);
  v.y = fmaxf(v.y / c + r.y, 0.f);
  v.z = fmaxf(v.z / c + r.z, 0.f);
  v.w = fmaxf(v.w / c + r.w, 0.f);
  reinterpret_cast<float4*>(out)[i] = v;
}

extern "C" void kernel_launch(void* const* d_in, const int* in_sizes, int n_in,
                              void* d_out, int out_size, void* d_ws, size_t ws_size,
                              hipStream_t stream) {
  const float* x = (const float*)d_in[0];
  const int* e0 = (const int*)d_in[1];
  const int* e1 = (const int*)d_in[2];
  const int* e2 = (const int*)d_in[3];
  const float* wq0 = (const float*)d_in[5];
  const float* bq0 = (const float*)d_in[6];
  const float* wk0 = (const float*)d_in[7];
  const float* bk0 = (const float*)d_in[8];
  const float* wv0 = (const float*)d_in[9];
  const float* bv0 = (const float*)d_in[10];
  const float* wq1 = (const float*)d_in[11];
  const float* bq1 = (const float*)d_in[12];
  const float* wk1 = (const float*)d_in[13];
  const float* bk1 = (const float*)d_in[14];
  const float* wv1 = (const float*)d_in[15];
  const float* bv1 = (const float*)d_in[16];
  const float* wq2 = (const float*)d_in[17];
  const float* bq2 = (const float*)d_in[18];
  const float* wk2 = (const float*)d_in[19];
  const float* bk2 = (const float*)d_in[20];
  const float* wv2 = (const float*)d_in[21];
  const float* bv2 = (const float*)d_in[22];

  const int N = in_sizes[0] / 128;  // 50000
  const int E = in_sizes[1] / 2;    // 500000
  const int NBLK = (N + 255) / 256;
  const int NP = NBLK * 256;
  const int RP = NP + 256;

  // ---- workspace carve-up (~52 MB) ----
  unsigned short* wp0 = (unsigned short*)d_ws;  // 98304 shorts
  unsigned short* wp1 = wp0 + 98304;            // 49152
  unsigned short* wp2 = wp1 + 49152;            // 49152
  float* s0 = (float*)(wp2 + 49152);            // N*128
  float* s1 = s0 + (size_t)N * 128;             // N*64
  int* hist = (int*)(s1 + (size_t)N * 64);      // 3*NP
  int* excl = hist + 3 * (size_t)NP;            // 3*NP
  int* bsum = excl + 3 * (size_t)NP;            // 3*256
  int* rowptr = bsum + 3 * 256;                 // 3*RP
  int* srcS = rowptr + 3 * (size_t)RP;          // 3*E
  int* dstS = srcS + 3 * (size_t)E;             // 3*E

  hipMemsetAsync(hist, 0, 3 * (size_t)NP * sizeof(int), stream);
  hipMemsetAsync(s0, 0, (size_t)N * 192 * sizeof(float), stream);
  hipMemsetAsync(d_out, 0, (size_t)out_size * sizeof(float), stream);

  pack_weights<<<48, 256, 0, stream>>>(wq0, wk0, wv0, wp0, 256, 128);
  pack_weights<<<24, 256, 0, stream>>>(wq1, wk1, wv1, wp1, 256, 64);
  pack_weights<<<24, 256, 0, stream>>>(wq2, wk2, wv2, wp2, 128, 128);

  const int EB256 = (E + 255) / 256;
  hist3<<<EB256, 256, 0, stream>>>(e0, e1, e2, E, hist, NP);
  scan_pass1<<<dim3(NBLK, 3), 256, 0, stream>>>(hist, excl, bsum, N, NP);
  scan_pass2<<<dim3(1, 3), 256, 0, stream>>>(bsum, NBLK);
  scan_pass3<<<dim3(NBLK, 3), 256, 0, stream>>>(excl, bsum, rowptr, N, NP, RP, E);
  scatter3<<<dim3(EB256, 3), 256, 0, stream>>>(e0, e1, e2, E, rowptr, hist, srcS, dstS, NP, RP);

  const int eb = (E + 63) / 64;
  edge_conv_kernel<128, 128, 16><<<eb, 256, 0, stream>>>(x, srcS, dstS, E, wp0, bq0, bk0, bv0, s0);
  finalize_relu<<<(N * 32 + 255) / 256, 256, 0, stream>>>(s0, rowptr, N * 32, 32);
  edge_conv_kernel<128, 64, 8><<<eb, 256, 0, stream>>>(s0, srcS + E, dstS + E, E, wp1, bq1, bk1, bv1, s1);
  finalize_relu<<<(N * 16 + 255) / 256, 256, 0, stream>>>(s1, rowptr + RP, N * 16, 16);
  edge_conv_kernel<64, 128, 16><<<eb, 256, 0, stream>>>(s1, srcS + 2 * (size_t)E, dstS + 2 * (size_t)E,
                                                        E, wp2, bq2, bk2, bv2, (float*)d_out);
  finalize_add_relu<<<(N * 32 + 255) / 256, 256, 0, stream>>>((float*)d_out, s0, rowptr + 2 * RP,
                                                              N * 32, 32);
}

// Round 3
// 759.502 us; speedup vs baseline: 1.6277x; 1.2502x over previous
//
#include <hip/hip_runtime.h>

// EdgeConvEncoder R3:
//  - feat@W = xi@(Wtop-Wbot) + xj@Wbot  -> no per-edge diff/convert
//  - node features pre-converted to bf16; gather via global_load_lds (async)
//  - XOR-swizzled unpadded LDS tiles (2-way bank alias only)
//  - 512-thread blocks, 64 edges, acc=48 regs/lane -> ~50% occupancy target

typedef short bf16x8 __attribute__((ext_vector_type(8)));
typedef float f32x4 __attribute__((ext_vector_type(4)));

__device__ __forceinline__ unsigned short f2bf(float f) {
  unsigned int u = __float_as_uint(f);
  u += 0x7FFFu + ((u >> 16) & 1u);  // round-to-nearest-even
  return (unsigned short)(u >> 16);
}

template <int HS>
__device__ __forceinline__ float head_reduce_sum(float v) {
  v += __shfl_xor(v, 1);
  v += __shfl_xor(v, 2);
  v += __shfl_xor(v, 4);
  if (HS == 16) v += __shfl_xor(v, 8);
  return v;
}

// ---------------- weight packing: 6 matrices (W1=top-bot x3, W2=bot x3) ----
// frag (mat, nc, kc): lane l, j -> Wm[kc*32 + (l>>4)*8 + j][nc*16 + (l&15)]
__global__ void pack_weights6(const float* __restrict__ wq, const float* __restrict__ wk,
                              const float* __restrict__ wv, unsigned short* __restrict__ dst,
                              int IN, int O) {
  int id = blockIdx.x * blockDim.x + threadIdx.x;
  int kchunks = IN >> 5, nchunks = O >> 4;
  int total = 6 * nchunks * kchunks * 64;
  if (id >= total) return;
  int lane = id & 63;
  int frag = id >> 6;
  int kc = frag % kchunks;
  int nc = (frag / kchunks) % nchunks;
  int mat = frag / (kchunks * nchunks);  // 0..2: W1(q,k,v)  3..5: W2(q,k,v)
  const float* w = (mat % 3 == 0) ? wq : (mat % 3 == 1) ? wk : wv;
  int n = nc * 16 + (lane & 15);
  int k0 = kc * 32 + (lane >> 4) * 8;
  unsigned short tmp[8];
#pragma unroll
  for (int j = 0; j < 8; ++j) {
    int row = k0 + j;
    float bot = w[(size_t)(IN + row) * O + n];
    float val = (mat < 3) ? (w[(size_t)row * O + n] - bot) : bot;
    tmp[j] = f2bf(val);
  }
  uint4 o;
  o.x = (unsigned)tmp[0] | ((unsigned)tmp[1] << 16);
  o.y = (unsigned)tmp[2] | ((unsigned)tmp[3] << 16);
  o.z = (unsigned)tmp[4] | ((unsigned)tmp[5] << 16);
  o.w = (unsigned)tmp[6] | ((unsigned)tmp[7] << 16);
  reinterpret_cast<uint4*>(dst)[id] = o;
}

// ---------------- counting sort by dst (per layer, batched via blockIdx.y) ---
__global__ void hist3(const int* __restrict__ e0, const int* __restrict__ e1,
                      const int* __restrict__ e2, int E, int* __restrict__ hist, int NP) {
  int i = blockIdx.x * blockDim.x + threadIdx.x;
  if (i >= E) return;
  atomicAdd(&hist[0 * NP + e0[E + i]], 1);
  atomicAdd(&hist[1 * NP + e1[E + i]], 1);
  atomicAdd(&hist[2 * NP + e2[E + i]], 1);
}

__device__ __forceinline__ int block_scan_excl256(int v, int* buf, int t, int* total) {
  buf[t] = v;
  __syncthreads();
#pragma unroll
  for (int off = 1; off < 256; off <<= 1) {
    int add = (t >= off) ? buf[t - off] : 0;
    __syncthreads();
    buf[t] += add;
    __syncthreads();
  }
  int incl = buf[t];
  *total = buf[255];
  __syncthreads();
  return incl - v;
}

__global__ void scan_pass1(const int* __restrict__ hist, int* __restrict__ excl,
                           int* __restrict__ bsum, int n, int NP) {
  __shared__ int buf[256];
  int y = blockIdx.y, t = threadIdx.x;
  int i = blockIdx.x * 256 + t;
  int v = (i < n) ? hist[y * NP + i] : 0;
  int total;
  int ex = block_scan_excl256(v, buf, t, &total);
  if (i < NP) excl[y * NP + i] = ex;
  if (t == 0) bsum[y * 256 + blockIdx.x] = total;
}

__global__ void scan_pass2(int* __restrict__ bsum, int nblk) {
  __shared__ int buf[256];
  int y = blockIdx.y, t = threadIdx.x;
  int v = (t < nblk) ? bsum[y * 256 + t] : 0;
  int total;
  int ex = block_scan_excl256(v, buf, t, &total);
  bsum[y * 256 + t] = ex;
}

__global__ void scan_pass3(const int* __restrict__ excl, const int* __restrict__ bsum,
                           int* __restrict__ rowptr, int n, int NP, int RP, int E) {
  int y = blockIdx.y;
  int i = blockIdx.x * 256 + threadIdx.x;
  if (i < n) rowptr[y * RP + i] = excl[y * NP + i] + bsum[y * 256 + blockIdx.x];
  if (i == 0) rowptr[y * RP + n] = E;
}

__global__ void scatter3(const int* __restrict__ e0, const int* __restrict__ e1,
                         const int* __restrict__ e2, int E, const int* __restrict__ rowptr,
                         int* __restrict__ hist, int* __restrict__ srcS,
                         int* __restrict__ dstS, int NP, int RP) {
  int y = blockIdx.y;
  const int* e = (y == 0) ? e0 : (y == 1) ? e1 : e2;
  int i = blockIdx.x * 256 + threadIdx.x;
  if (i >= E) return;
  int sN = e[i], d = e[E + i];
  int old = atomicSub(&hist[y * NP + d], 1);
  int pos = rowptr[y * RP + d] + old - 1;
  srcS[(size_t)y * E + pos] = sN;
  dstS[(size_t)y * E + pos] = d;
}

// ---------------- fused EdgeConv layer ----------------
// 512 threads = 8 waves, 64 dst-sorted edges. q/k/v = xi@W1 + xj@W2 + b.
// xi rows 0..63, xj rows 64..127 in un-padded LDS (XOR chunk swizzle),
// staged async via global_load_lds. Wave owns col-chunk(s); softmax wave-local.
template <int IN, int O, int HS>
__global__ __launch_bounds__(512, 4) void edge_conv_kernel(
    const unsigned short* __restrict__ xb, const int* __restrict__ srcS,
    const int* __restrict__ dstS, const int E,
    const unsigned short* __restrict__ wpack, const float* __restrict__ bq,
    const float* __restrict__ bk, const float* __restrict__ bv,
    float* __restrict__ s) {
  constexpr int KC = IN / 32;            // 32-wide k-chunks
  constexpr int NCH = O / 16;            // 16-col output chunks
  constexpr int CHR = IN / 8;            // 16B chunks per feature row
  constexpr int CM = CHR - 1;            // swizzle mask
  constexpr int CSTR = O + 4;            // f32 ctx stride
  constexpr int MW = (NCH >= 8) ? 4 : 2; // m-tiles per wave
  constexpr float scale = (HS == 16) ? 0.25f : 0.35355339059327373f;

  __shared__ union {
    unsigned short tiles[128 * IN];  // xi rows [0,64), xj rows [64,128)
    float ctx[64 * CSTR];
  } sm;
  __shared__ int dstL[64];
  __shared__ float ewL[64];

  const int t = threadIdx.x;
  const int w = t >> 6;
  const int ln = t & 63;
  const int e0 = blockIdx.x * 64;

  if (t < 64) {
    int eIdx = min(e0 + t, E - 1);
    int sN = srcS[eIdx], dN = dstS[eIdx];
    dstL[t] = dN;
    float dd = fabsf((float)(dN - sN));
    ewL[t] = (dd > 8.0f) ? 1.0f : ((dd == 8.0f) ? 0.0f : -1.0f);
  }

  {  // async gather: each wave stages 16 of the 128 rows
    constexpr int RPI = 64 / CHR;  // rows per instruction (4 or 8)
    constexpr int NI = 16 / RPI;   // instructions per wave (4 or 2)
    const int r_in = ln / CHR;
    const int c = ln % CHR;
#pragma unroll
    for (int i = 0; i < NI; ++i) {
      int row = w * 16 + i * RPI + r_in;  // 0..127
      int edge = row & 63;
      int eIdx = min(e0 + edge, E - 1);
      int node = (row < 64) ? dstS[eIdx] : srcS[eIdx];
      int sc = c ^ (edge & CM);  // stored chunk c holds source chunk sc
      const unsigned short* g = xb + (size_t)node * IN + sc * 8;
      unsigned short* l = &sm.tiles[(size_t)(w * 16 + i * RPI) * IN];  // wave-uniform
      __builtin_amdgcn_global_load_lds(
          (const __attribute__((address_space(1))) unsigned int*)g,
          (__attribute__((address_space(3))) unsigned int*)l, 16, 0, 0);
    }
  }
  __syncthreads();

  const int col = ln & 15;
  const int quad = ln >> 4;
  const int chunkw = (NCH >= 8) ? w : (w >> 1);
  const int m0 = (NCH >= 8) ? 0 : (w & 1) * MW;

  f32x4 acc[3][MW];
#pragma unroll
  for (int mat = 0; mat < 3; ++mat)
#pragma unroll
    for (int m = 0; m < MW; ++m) acc[mat][m] = (f32x4){0.f, 0.f, 0.f, 0.f};

#pragma unroll
  for (int kc = 0; kc < KC; ++kc) {
    bf16x8 aI[MW], aJ[MW];
#pragma unroll
    for (int m = 0; m < MW; ++m) {
      int edge = (m0 + m) * 16 + col;
      int sc = (kc * 4 + quad) ^ (edge & CM);  // un-swizzle
      aI[m] = *reinterpret_cast<const bf16x8*>(&sm.tiles[(size_t)edge * IN + sc * 8]);
      aJ[m] = *reinterpret_cast<const bf16x8*>(&sm.tiles[(size_t)(64 + edge) * IN + sc * 8]);
    }
#pragma unroll
    for (int mat = 0; mat < 3; ++mat) {
      const bf16x8 bI = *reinterpret_cast<const bf16x8*>(
          wpack + ((size_t)((mat * NCH + chunkw) * KC + kc) * 64 + ln) * 8);
      const bf16x8 bJ = *reinterpret_cast<const bf16x8*>(
          wpack + ((size_t)(((mat + 3) * NCH + chunkw) * KC + kc) * 64 + ln) * 8);
#pragma unroll
      for (int m = 0; m < MW; ++m) {
        acc[mat][m] = __builtin_amdgcn_mfma_f32_16x16x32_bf16(aI[m], bI, acc[mat][m], 0, 0, 0);
        acc[mat][m] = __builtin_amdgcn_mfma_f32_16x16x32_bf16(aJ[m], bJ, acc[mat][m], 0, 0, 0);
      }
    }
  }
  __syncthreads();  // tiles dead; union becomes ctx

  // Epilogue: bias + softmax(q*k*scale) + v*ew -> LDS ctx.
  // C-frag: col = ln&15, row(edge) = m-tile*16 + quad*4 + r.
  {
    const int colg = chunkw * 16 + col;
    const float bqv = bq[colg], bkv = bk[colg], bvv = bv[colg];
#pragma unroll
    for (int m = 0; m < MW; ++m) {
      const f32x4 qf = acc[0][m];
      const f32x4 kf = acc[1][m];
      const f32x4 vf = acc[2][m];
#pragma unroll
      for (int r = 0; r < 4; ++r) {
        const int eRow = (m0 + m) * 16 + quad * 4 + r;
        float lg = (qf[r] + bqv) * (kf[r] + bkv) * scale;
        float ex = __expf(lg);
        float sum = head_reduce_sum<HS>(ex);
        float val = (ex / sum) * (vf[r] + bvv) * ewL[eRow];
        sm.ctx[eRow * CSTR + colg] = (e0 + eRow < E) ? val : 0.f;
      }
    }
  }
  __syncthreads();

  // Segmented reduction: one atomic per (dst-segment x column).
  {
    constexpr int GRP = 512 / O;
    constexpr int EPT = 64 / GRP;
    const int colA = t % O;
    const int seg0 = (t / O) * EPT;
    float run = 0.f;
    for (int e = seg0; e < seg0 + EPT; ++e) {
      run += sm.ctx[e * CSTR + colA];
      bool bound = (e == seg0 + EPT - 1) || (dstL[e + 1] != dstL[e]);
      if (bound) {
        atomicAdd(&s[(size_t)dstL[e] * O + colA], run);
        run = 0.f;
      }
    }
  }
}

// ---------------- conversions / finalize ----------------
__global__ void f32_to_bf16(const float* __restrict__ in, unsigned short* __restrict__ out,
                            int n8) {
  int i = blockIdx.x * blockDim.x + threadIdx.x;
  if (i >= n8) return;
  float4 a = reinterpret_cast<const float4*>(in)[2 * i];
  float4 b = reinterpret_cast<const float4*>(in)[2 * i + 1];
  uint4 o;
  o.x = (unsigned)f2bf(a.x) | ((unsigned)f2bf(a.y) << 16);
  o.y = (unsigned)f2bf(a.z) | ((unsigned)f2bf(a.w) << 16);
  o.z = (unsigned)f2bf(b.x) | ((unsigned)f2bf(b.y) << 16);
  o.w = (unsigned)f2bf(b.z) | ((unsigned)f2bf(b.w) << 16);
  reinterpret_cast<uint4*>(out)[i] = o;
}

// s = relu(s/cnt) (f32, kept for residual) and bf16 copy for next layer.
__global__ void finalize_relu_f32bf16(float* __restrict__ s, const int* __restrict__ rowptr,
                                      unsigned short* __restrict__ xbo, int total4, int Odiv4) {
  int i = blockIdx.x * blockDim.x + threadIdx.x;
  if (i >= total4) return;
  int node = i / Odiv4;
  float c = fmaxf((float)(rowptr[node + 1] - rowptr[node]), 1.0f);
  float4 v = reinterpret_cast<float4*>(s)[i];
  v.x = fmaxf(v.x / c, 0.f);
  v.y = fmaxf(v.y / c, 0.f);
  v.z = fmaxf(v.z / c, 0.f);
  v.w = fmaxf(v.w / c, 0.f);
  reinterpret_cast<float4*>(s)[i] = v;
  ushort4 o = make_ushort4(f2bf(v.x), f2bf(v.y), f2bf(v.z), f2bf(v.w));
  reinterpret_cast<ushort4*>(xbo)[i] = o;
}

// bf16-only finalize (layer1 output feeds only layer2).
__global__ void finalize_relu_bf16(const float* __restrict__ s, const int* __restrict__ rowptr,
                                   unsigned short* __restrict__ xbo, int total4, int Odiv4) {
  int i = blockIdx.x * blockDim.x + threadIdx.x;
  if (i >= total4) return;
  int node = i / Odiv4;
  float c = fmaxf((float)(rowptr[node + 1] - rowptr[node]), 1.0f);
  float4 v = reinterpret_cast<const float4*>(s)[i];
  ushort4 o = make_ushort4(f2bf(fmaxf(v.x / c, 0.f)), f2bf(fmaxf(v.y / c, 0.f)),
                           f2bf(fmaxf(v.z / c, 0.f)), f2bf(fmaxf(v.w / c, 0.f)));
  reinterpret_cast<ushort4*>(xbo)[i] = o;
}

__global__ void finalize_add_relu(float* __restrict__ out, const float* __restrict__ x0,
                                  const int* __restrict__ rowptr, int total4, int Odiv4) {
  int i = blockIdx.x * blockDim.x + threadIdx.x;
  if (i >= total4) return;
  int node = i / Odiv4;
  float c = fmaxf((float)(rowptr[node + 1] - rowptr[node]), 1.0f);
  float4 v = reinterpret_cast<float4*>(out)[i];
  float4 r = reinterpret_cast<const float4*>(x0)[i];
  v.x = fmaxf(v.x / c + r.x, 0.f);
  v.y = fmaxf(v.y / c + r.y, 0.f);
  v.z = fmaxf(v.z / c + r.z, 0.f);
  v.w = fmaxf(v.w / c + r.w, 0.f);
  reinterpret_cast<float4*>(out)[i] = v;
}

extern "C" void kernel_launch(void* const* d_in, const int* in_sizes, int n_in,
                              void* d_out, int out_size, void* d_ws, size_t ws_size,
                              hipStream_t stream) {
  const float* x = (const float*)d_in[0];
  const int* e0 = (const int*)d_in[1];
  const int* e1 = (const int*)d_in[2];
  const int* e2 = (const int*)d_in[3];
  const float* wq0 = (const float*)d_in[5];
  const float* bq0 = (const float*)d_in[6];
  const float* wk0 = (const float*)d_in[7];
  const float* bk0 = (const float*)d_in[8];
  const float* wv0 = (const float*)d_in[9];
  const float* bv0 = (const float*)d_in[10];
  const float* wq1 = (const float*)d_in[11];
  const float* bq1 = (const float*)d_in[12];
  const float* wk1 = (const float*)d_in[13];
  const float* bk1 = (const float*)d_in[14];
  const float* wv1 = (const float*)d_in[15];
  const float* bv1 = (const float*)d_in[16];
  const float* wq2 = (const float*)d_in[17];
  const float* bq2 = (const float*)d_in[18];
  const float* wk2 = (const float*)d_in[19];
  const float* bk2 = (const float*)d_in[20];
  const float* wv2 = (const float*)d_in[21];
  const float* bv2 = (const float*)d_in[22];

  const int N = in_sizes[0] / 128;  // 50000
  const int E = in_sizes[1] / 2;    // 500000
  const int NBLK = (N + 255) / 256;
  const int NP = NBLK * 256;
  const int RP = NP + 256;

  // ---- workspace carve-up ----
  unsigned short* wp0 = (unsigned short*)d_ws;     // 6*8*4*64*8 = 98304 shorts
  unsigned short* wp1 = wp0 + 98304;               // 6*4*4*64*8 = 49152
  unsigned short* wp2 = wp1 + 49152;               // 6*8*2*64*8 = 49152
  unsigned short* xb0 = wp2 + 49152;               // N*128
  unsigned short* xb1 = xb0 + (size_t)N * 128;     // N*128
  unsigned short* xb2 = xb1 + (size_t)N * 128;     // N*64
  float* s0 = (float*)(xb2 + (size_t)N * 64);      // N*128
  float* s1 = s0 + (size_t)N * 128;                // N*64
  int* hist = (int*)(s1 + (size_t)N * 64);         // 3*NP
  int* excl = hist + 3 * (size_t)NP;               // 3*NP
  int* bsum = excl + 3 * (size_t)NP;               // 3*256
  int* rowptr = bsum + 3 * 256;                    // 3*RP
  int* srcS = rowptr + 3 * (size_t)RP;             // 3*E
  int* dstS = srcS + 3 * (size_t)E;                // 3*E

  hipMemsetAsync(hist, 0, 3 * (size_t)NP * sizeof(int), stream);
  hipMemsetAsync(s0, 0, (size_t)N * 192 * sizeof(float), stream);
  hipMemsetAsync(d_out, 0, (size_t)out_size * sizeof(float), stream);

  pack_weights6<<<48, 256, 0, stream>>>(wq0, wk0, wv0, wp0, 128, 128);
  pack_weights6<<<24, 256, 0, stream>>>(wq1, wk1, wv1, wp1, 128, 64);
  pack_weights6<<<24, 256, 0, stream>>>(wq2, wk2, wv2, wp2, 64, 128);
  f32_to_bf16<<<(N * 16 + 255) / 256, 256, 0, stream>>>(x, xb0, N * 16);

  const int EB256 = (E + 255) / 256;
  hist3<<<EB256, 256, 0, stream>>>(e0, e1, e2, E, hist, NP);
  scan_pass1<<<dim3(NBLK, 3), 256, 0, stream>>>(hist, excl, bsum, N, NP);
  scan_pass2<<<dim3(1, 3), 256, 0, stream>>>(bsum, NBLK);
  scan_pass3<<<dim3(NBLK, 3), 256, 0, stream>>>(excl, bsum, rowptr, N, NP, RP, E);
  scatter3<<<dim3(EB256, 3), 256, 0, stream>>>(e0, e1, e2, E, rowptr, hist, srcS, dstS, NP, RP);

  const int eb = (E + 63) / 64;
  edge_conv_kernel<128, 128, 16><<<eb, 512, 0, stream>>>(xb0, srcS, dstS, E, wp0, bq0, bk0, bv0, s0);
  finalize_relu_f32bf16<<<(N * 32 + 255) / 256, 256, 0, stream>>>(s0, rowptr, xb1, N * 32, 32);
  edge_conv_kernel<128, 64, 8><<<eb, 512, 0, stream>>>(xb1, srcS + E, dstS + E, E, wp1, bq1, bk1, bv1, s1);
  finalize_relu_bf16<<<(N * 16 + 255) / 256, 256, 0, stream>>>(s1, rowptr + RP, xb2, N * 16, 16);
  edge_conv_kernel<64, 128, 16><<<eb, 512, 0, stream>>>(xb2, srcS + 2 * (size_t)E, dstS + 2 * (size_t)E,
                                                        E, wp2, bq2, bk2, bv2, (float*)d_out);
  finalize_add_relu<<<(N * 32 + 255) / 256, 256, 0, stream>>>((float*)d_out, s0, rowptr + 2 * RP,
                                                              N * 32, 32);
}